// Round 1
// baseline (502.700 us; speedup 1.0000x reference)
//
#include <hip/hip_runtime.h>
#include <stdint.h>

typedef unsigned short u16;
typedef short bf16x8 __attribute__((ext_vector_type(8)));
typedef float f32x4 __attribute__((ext_vector_type(4)));

#define CTX 2048
#define DIN 1024
#define DOUT 1024
#define NB 8

__device__ __forceinline__ u16 f2bf(float f) {
  uint32_t u = __builtin_bit_cast(uint32_t, f);
  u += 0x7FFFu + ((u >> 16) & 1u);
  return (u16)(u >> 16);
}

// global -> LDS async, 16B per lane. LDS dest is wave-uniform base + lane*16.
__device__ __forceinline__ void gld_lds16(const u16* g, const u16* lds) {
  __builtin_amdgcn_global_load_lds(
      (const __attribute__((address_space(1))) uint32_t*)(unsigned long long)(const void*)g,
      (__attribute__((address_space(3))) uint32_t*)(uint32_t)(unsigned long long)(const void*)lds,
      16, 0, 0);
}

// ---------------------------------------------------------------------------
// m97-structure GEMM core: C[128x128] tile = A[128xK] * Bt[128xK]^T
// A row-major [M][K] (lda elems), Bt row-major [N][K] (ldb elems), bf16.
// 4 waves, each owns a 64x64 quadrant = 4x4 frags of 16x16, mfma_16x16x32_bf16.
// LDS tiles stored in fragment order: [8 fragrows][64 lanes][8 elems] so that
// staging (global_load_lds, linear dest) and ds_read_b128 are both conflict-free.
// CMODE: 0 = bf16 row-major C; 1 = bf16 transposed C (vT[b][n][s], batch from m0);
//        2 = fp32 C with scale.
// ---------------------------------------------------------------------------
template <int CMODE>
__device__ __forceinline__ void gemm_core(const u16* __restrict__ A, int lda,
                                          const u16* __restrict__ Bt, int ldb,
                                          int m0, int n0, int K,
                                          void* __restrict__ Cp, int ldc,
                                          float scale) {
  __shared__ u16 As[128 * 32];
  __shared__ u16 Bs[128 * 32];

  const int t = threadIdx.x;
  const int lane = t & 63;
  const int wid = t >> 6;   // 0..3
  const int wr = wid >> 1;  // 0..1 (m quadrant)
  const int wc = wid & 1;   // 0..1 (n quadrant)
  const int l15 = lane & 15;
  const int l16 = lane >> 4;  // 0..3

  f32x4 acc[4][4];
#pragma unroll
  for (int i = 0; i < 4; ++i)
#pragma unroll
    for (int j = 0; j < 4; ++j) acc[i][j] = {0.f, 0.f, 0.f, 0.f};

  // staging: round 0 covers fragrows 0..3 (tile rows 0..63), round 1 rows 64..127
  const int rowA = wid * 16 + l15;
  const int kk = l16 * 8;
  const u16* gA0 = A + (size_t)(m0 + rowA) * lda + kk;
  const u16* gA1 = gA0 + (size_t)64 * lda;
  const u16* gB0 = Bt + (size_t)(n0 + rowA) * ldb + kk;
  const u16* gB1 = gB0 + (size_t)64 * ldb;
  u16* lA0 = As + wid * 512;        // wave-uniform LDS bases
  u16* lA1 = As + (4 + wid) * 512;
  u16* lB0 = Bs + wid * 512;
  u16* lB1 = Bs + (4 + wid) * 512;

  for (int kt = 0; kt < K; kt += 32) {
    gld_lds16(gA0, lA0);
    gld_lds16(gA1, lA1);
    gld_lds16(gB0, lB0);
    gld_lds16(gB1, lB1);
    gA0 += 32; gA1 += 32; gB0 += 32; gB1 += 32;
    __syncthreads();  // drains vmcnt(0) -> LDS tiles ready
    bf16x8 af[4], bfr[4];
#pragma unroll
    for (int mi = 0; mi < 4; ++mi)
      af[mi] = *reinterpret_cast<const bf16x8*>(As + ((wr * 4 + mi) * 64 + lane) * 8);
#pragma unroll
    for (int nj = 0; nj < 4; ++nj)
      bfr[nj] = *reinterpret_cast<const bf16x8*>(Bs + ((wc * 4 + nj) * 64 + lane) * 8);
#pragma unroll
    for (int mi = 0; mi < 4; ++mi)
#pragma unroll
      for (int nj = 0; nj < 4; ++nj)
        acc[mi][nj] = __builtin_amdgcn_mfma_f32_16x16x32_bf16(af[mi], bfr[nj],
                                                              acc[mi][nj], 0, 0, 0);
    __syncthreads();  // before next overwrite of LDS
  }

  // epilogue: C row = m0 + wr*64 + mi*16 + l16*4 + i ; col = n0 + wc*64 + nj*16 + l15
  const int r0 = wr * 64 + l16 * 4;
  const int c0 = wc * 64 + l15;
  if constexpr (CMODE == 0) {
    u16* C = (u16*)Cp;
#pragma unroll
    for (int mi = 0; mi < 4; ++mi)
#pragma unroll
      for (int nj = 0; nj < 4; ++nj) {
        const int r = m0 + r0 + mi * 16;
        const int c = n0 + c0 + nj * 16;
#pragma unroll
        for (int i = 0; i < 4; ++i)
          C[(size_t)(r + i) * ldc + c] = f2bf(acc[mi][nj][i]);
      }
  } else if constexpr (CMODE == 1) {
    // transposed write into vT[b][n][s]; batch = m0>>11 (tile never crosses batch)
    u16* C = (u16*)Cp + ((size_t)(m0 >> 11)) * DOUT * CTX;
    const int sl = (m0 & (CTX - 1)) + r0;
#pragma unroll
    for (int mi = 0; mi < 4; ++mi)
#pragma unroll
      for (int nj = 0; nj < 4; ++nj) {
        const int c = n0 + c0 + nj * 16;
        const int s = sl + mi * 16;
        ushort4 o;
        o.x = f2bf(acc[mi][nj][0]);
        o.y = f2bf(acc[mi][nj][1]);
        o.z = f2bf(acc[mi][nj][2]);
        o.w = f2bf(acc[mi][nj][3]);
        *reinterpret_cast<ushort4*>(C + (size_t)c * CTX + s) = o;
      }
  } else {
    float* C = (float*)Cp;
#pragma unroll
    for (int mi = 0; mi < 4; ++mi)
#pragma unroll
      for (int nj = 0; nj < 4; ++nj) {
        const int r = m0 + r0 + mi * 16;
        const int c = n0 + c0 + nj * 16;
#pragma unroll
        for (int i = 0; i < 4; ++i)
          C[(size_t)(r + i) * ldc + c] = acc[mi][nj][i] * scale;
      }
  }
}

// ---------------------------------------------------------------------------
__global__ __launch_bounds__(256) void k_cvt_x(const float* __restrict__ x,
                                               u16* __restrict__ xb) {
  const int idx = (blockIdx.x * 256 + threadIdx.x) * 4;
  const float4 v = *reinterpret_cast<const float4*>(x + idx);
  ushort4 o;
  o.x = f2bf(v.x); o.y = f2bf(v.y); o.z = f2bf(v.z); o.w = f2bf(v.w);
  *reinterpret_cast<ushort4*>(xb + idx) = o;
}

// W [DIN][DOUT] fp32 -> Wt [DOUT][DIN] bf16 (tiled transpose via LDS)
__global__ __launch_bounds__(256) void k_cvt_wt(const float* __restrict__ W,
                                                u16* __restrict__ Wt) {
  __shared__ u16 tile[64][65];
  const int bc = blockIdx.x;
  const int tr0 = (bc >> 4) * 64;  // k
  const int tc0 = (bc & 15) * 64;  // n
  const int t = threadIdx.x;
  const int col = t & 63, rr = t >> 6;
#pragma unroll
  for (int p = 0; p < 16; ++p) {
    const int row = rr * 16 + p;
    tile[row][col] = f2bf(W[(size_t)(tr0 + row) * DOUT + tc0 + col]);
  }
  __syncthreads();
#pragma unroll
  for (int p = 0; p < 16; ++p) {
    const int row = rr * 16 + p;
    Wt[(size_t)(tc0 + row) * DIN + tr0 + col] = tile[col][row];
  }
}

__global__ __launch_bounds__(256) void k_proj_rm(const u16* __restrict__ xb,
                                                 const u16* __restrict__ Wt,
                                                 u16* __restrict__ C) {
  const int m0 = blockIdx.y * 128, n0 = blockIdx.x * 128;
  gemm_core<0>(xb, DIN, Wt, DIN, m0, n0, DIN, C, DOUT, 1.0f);
}

__global__ __launch_bounds__(256) void k_proj_tr(const u16* __restrict__ xb,
                                                 const u16* __restrict__ Wt,
                                                 u16* __restrict__ vT) {
  const int m0 = blockIdx.y * 128, n0 = blockIdx.x * 128;
  gemm_core<1>(xb, DIN, Wt, DIN, m0, n0, DIN, vT, CTX, 1.0f);
}

// S[b][i][j] = (q.k)/32 for lower-triangular 128x128 tiles only
__global__ __launch_bounds__(256) void k_score(const u16* __restrict__ qb,
                                               const u16* __restrict__ kb,
                                               float* __restrict__ S) {
  const int u = blockIdx.x, b = blockIdx.y;
  int it = (int)((sqrtf(8.0f * u + 1.0f) - 1.0f) * 0.5f);
  while ((it + 1) * (it + 2) / 2 <= u) ++it;
  while (it * (it + 1) / 2 > u) --it;
  const int jt = u - it * (it + 1) / 2;
  const u16* Aq = qb + (size_t)b * CTX * DOUT;
  const u16* Bk = kb + (size_t)b * CTX * DOUT;
  float* C = S + ((size_t)b << 22);
  gemm_core<2>(Aq, DOUT, Bk, DOUT, it * 128, jt * 128, DOUT, C, CTX, 0.03125f);
}

// row softmax over S fp32, write P bf16 in place (row stride 8192B = 4096 u16),
// full 2048 cols written (zeros above diagonal) so PV GEMM needs no masking.
__global__ __launch_bounds__(256) void k_softmax(float* __restrict__ Sws) {
  const int row = blockIdx.x;
  const int b = row >> 11, i = row & (CTX - 1);
  const float* srow = Sws + ((size_t)b << 22) + ((size_t)i << 11);
  u16* prow = (u16*)(Sws + ((size_t)b << 22)) + ((size_t)i << 12);
  const int t = threadIdx.x;
  const int j0 = t * 8;
  const float4 v0 = *reinterpret_cast<const float4*>(srow + j0);
  const float4 v1 = *reinterpret_cast<const float4*>(srow + j0 + 4);
  float vv[8] = {v0.x, v0.y, v0.z, v0.w, v1.x, v1.y, v1.z, v1.w};
  float mx = -3.0e38f;
#pragma unroll
  for (int p = 0; p < 8; ++p) {
    vv[p] = (j0 + p <= i) ? vv[p] : -3.0e38f;  // also kills poison/NaN
    mx = fmaxf(mx, vv[p]);
  }
#pragma unroll
  for (int off = 32; off > 0; off >>= 1) mx = fmaxf(mx, __shfl_xor(mx, off));
  __shared__ float redm[4], reds[4];
  const int lane = t & 63, wid = t >> 6;
  if (lane == 0) redm[wid] = mx;
  __syncthreads();
  mx = fmaxf(fmaxf(redm[0], redm[1]), fmaxf(redm[2], redm[3]));
  float e[8], s = 0.f;
#pragma unroll
  for (int p = 0; p < 8; ++p) {
    e[p] = __expf(vv[p] - mx);
    s += e[p];
  }
#pragma unroll
  for (int off = 32; off > 0; off >>= 1) s += __shfl_xor(s, off);
  if (lane == 0) reds[wid] = s;
  __syncthreads();  // also orders: all row reads above happen before writes below
  s = reds[0] + reds[1] + reds[2] + reds[3];
  const float inv = 1.0f / s;
  ushort4 o0, o1;
  o0.x = (j0 + 0 <= i) ? f2bf(e[0] * inv) : (u16)0;
  o0.y = (j0 + 1 <= i) ? f2bf(e[1] * inv) : (u16)0;
  o0.z = (j0 + 2 <= i) ? f2bf(e[2] * inv) : (u16)0;
  o0.w = (j0 + 3 <= i) ? f2bf(e[3] * inv) : (u16)0;
  o1.x = (j0 + 4 <= i) ? f2bf(e[4] * inv) : (u16)0;
  o1.y = (j0 + 5 <= i) ? f2bf(e[5] * inv) : (u16)0;
  o1.z = (j0 + 6 <= i) ? f2bf(e[6] * inv) : (u16)0;
  o1.w = (j0 + 7 <= i) ? f2bf(e[7] * inv) : (u16)0;
  *reinterpret_cast<ushort4*>(prow + j0) = o0;
  *reinterpret_cast<ushort4*>(prow + j0 + 4) = o1;
}

// out[b][i][d] = sum_j P[b][i][j] * V[b][j][d], K-loop causally limited
__global__ __launch_bounds__(256) void k_out(const float* __restrict__ Sws,
                                             const u16* __restrict__ vT,
                                             float* __restrict__ out) {
  const int nt = blockIdx.x, it = blockIdx.y, b = blockIdx.z;
  const u16* P = (const u16*)(Sws + ((size_t)b << 22));  // lda = 4096 u16
  const u16* Bt = vT + (size_t)b * DOUT * CTX;           // [D][S], ldb = 2048
  float* C = out + (size_t)b * CTX * DOUT;
  gemm_core<2>(P, 2 * CTX, Bt, CTX, it * 128, nt * 128, (it + 1) * 128, C, DOUT, 1.0f);
}

// ---------------------------------------------------------------------------
extern "C" void kernel_launch(void* const* d_in, const int* in_sizes, int n_in,
                              void* d_out, int out_size, void* d_ws, size_t ws_size,
                              hipStream_t stream) {
  (void)in_sizes; (void)n_in; (void)out_size; (void)ws_size;
  const float* x = (const float*)d_in[0];
  const float* Wq = (const float*)d_in[1];
  const float* Wk = (const float*)d_in[2];
  const float* Wv = (const float*)d_in[3];
  float* out = (float*)d_out;
  uint8_t* ws = (uint8_t*)d_ws;

  // ws layout (224 MB total):
  //   [0,128M): S fp32 [8][2048][2048]  (P bf16 written in place by softmax)
  //     xb bf16 (32MB) and Wt's (6MB) overlap S -- dead before k_score runs
  //   [128M,160M): qb  [160M,192M): kb  [192M,224M): vT [8][1024][2048]
  float* S = (float*)ws;
  u16* xb = (u16*)ws;
  u16* Wqt = (u16*)(ws + 33554432ull);
  u16* Wkt = (u16*)(ws + 35651584ull);
  u16* Wvt = (u16*)(ws + 37748736ull);
  u16* qb = (u16*)(ws + 134217728ull);
  u16* kb = (u16*)(ws + 167772160ull);
  u16* vT = (u16*)(ws + 201326592ull);

  k_cvt_x<<<16384, 256, 0, stream>>>(x, xb);
  k_cvt_wt<<<256, 256, 0, stream>>>(Wq, Wqt);
  k_cvt_wt<<<256, 256, 0, stream>>>(Wk, Wkt);
  k_cvt_wt<<<256, 256, 0, stream>>>(Wv, Wvt);
  const dim3 gp(DOUT / 128, (NB * CTX) / 128);
  k_proj_rm<<<gp, 256, 0, stream>>>(xb, Wqt, qb);
  k_proj_rm<<<gp, 256, 0, stream>>>(xb, Wkt, kb);
  k_proj_tr<<<gp, 256, 0, stream>>>(xb, Wvt, vT);
  k_score<<<dim3(136, NB), 256, 0, stream>>>(qb, kb, S);
  k_softmax<<<NB * CTX, 256, 0, stream>>>(S);
  k_out<<<dim3(DOUT / 128, CTX / 128, NB), 256, 0, stream>>>(S, vT, out);
}

// Round 2
// 434.934 us; speedup vs baseline: 1.1558x; 1.1558x over previous
//
#include <hip/hip_runtime.h>
#include <stdint.h>

typedef unsigned short u16;
typedef short bf16x8 __attribute__((ext_vector_type(8)));
typedef float f32x4 __attribute__((ext_vector_type(4)));

#define CTX 2048
#define DIN 1024
#define DOUT 1024
#define NB 8

__device__ __forceinline__ u16 f2bf(float f) {
  uint32_t u = __builtin_bit_cast(uint32_t, f);
  u += 0x7FFFu + ((u >> 16) & 1u);
  return (u16)(u >> 16);
}

// global -> LDS async, 16B per lane. LDS dest is wave-uniform base + lane*16.
__device__ __forceinline__ void gld_lds16(const u16* g, const u16* lds) {
  __builtin_amdgcn_global_load_lds(
      (const __attribute__((address_space(1))) uint32_t*)(unsigned long long)(const void*)g,
      (__attribute__((address_space(3))) uint32_t*)(uint32_t)(unsigned long long)(const void*)lds,
      16, 0, 0);
}

// ---------------------------------------------------------------------------
// m97-structure GEMM core: 128x128 C tile = A[128xK] * Bt[128xK]^T, bf16.
// 4 waves, each owns a 64x64 quadrant = 4x4 frags of 16x16 (mfma_16x16x32_bf16).
// LDS tiles in fragment order [8 fragrows][64 lanes][8 elems]: staging
// (global_load_lds, linear dest) and ds_read_b128 both conflict-free.
// Epilogue supplied by caller: epi(acc, r0, c0) with tile-local coords
// row = r0 + mi*16 + i (i=0..3), col = c0 + nj*16.
// ---------------------------------------------------------------------------
template <typename EPI>
__device__ __forceinline__ void gemm_core(const u16* __restrict__ A, int lda,
                                          const u16* __restrict__ Bt, int ldb,
                                          int m0, int n0, int K, EPI&& epi) {
  __shared__ __align__(16) u16 As[128 * 32];
  __shared__ __align__(16) u16 Bs[128 * 32];

  const int t = threadIdx.x;
  const int lane = t & 63;
  const int wid = t >> 6;   // 0..3
  const int wr = wid >> 1;  // m quadrant
  const int wc = wid & 1;   // n quadrant
  const int l15 = lane & 15;
  const int l16 = lane >> 4;  // 0..3

  f32x4 acc[4][4];
#pragma unroll
  for (int i = 0; i < 4; ++i)
#pragma unroll
    for (int j = 0; j < 4; ++j) acc[i][j] = {0.f, 0.f, 0.f, 0.f};

  const int rowA = wid * 16 + l15;
  const int kk = l16 * 8;
  const u16* gA0 = A + (size_t)(m0 + rowA) * lda + kk;
  const u16* gA1 = gA0 + (size_t)64 * lda;
  const u16* gB0 = Bt + (size_t)(n0 + rowA) * ldb + kk;
  const u16* gB1 = gB0 + (size_t)64 * ldb;
  u16* lA0 = As + wid * 512;
  u16* lA1 = As + (4 + wid) * 512;
  u16* lB0 = Bs + wid * 512;
  u16* lB1 = Bs + (4 + wid) * 512;

  for (int kt = 0; kt < K; kt += 32) {
    gld_lds16(gA0, lA0);
    gld_lds16(gA1, lA1);
    gld_lds16(gB0, lB0);
    gld_lds16(gB1, lB1);
    gA0 += 32; gA1 += 32; gB0 += 32; gB1 += 32;
    __syncthreads();  // drains vmcnt(0) -> LDS tiles ready
    bf16x8 af[4], bfr[4];
#pragma unroll
    for (int mi = 0; mi < 4; ++mi)
      af[mi] = *reinterpret_cast<const bf16x8*>(As + ((wr * 4 + mi) * 64 + lane) * 8);
#pragma unroll
    for (int nj = 0; nj < 4; ++nj)
      bfr[nj] = *reinterpret_cast<const bf16x8*>(Bs + ((wc * 4 + nj) * 64 + lane) * 8);
#pragma unroll
    for (int mi = 0; mi < 4; ++mi)
#pragma unroll
      for (int nj = 0; nj < 4; ++nj)
        acc[mi][nj] = __builtin_amdgcn_mfma_f32_16x16x32_bf16(af[mi], bfr[nj],
                                                              acc[mi][nj], 0, 0, 0);
    __syncthreads();  // before next overwrite of LDS
  }

  const int r0 = wr * 64 + l16 * 4;
  const int c0 = wc * 64 + l15;
  epi(acc, r0, c0);
}

// ---------------------------------------------------------------------------
__global__ __launch_bounds__(256) void k_cvt_x(const float* __restrict__ x,
                                               u16* __restrict__ xb) {
  const int idx = (blockIdx.x * 256 + threadIdx.x) * 4;
  const float4 v = *reinterpret_cast<const float4*>(x + idx);
  ushort4 o;
  o.x = f2bf(v.x); o.y = f2bf(v.y); o.z = f2bf(v.z); o.w = f2bf(v.w);
  *reinterpret_cast<ushort4*>(xb + idx) = o;
}

// W [DIN][DOUT] fp32 -> Wt [DOUT][DIN] bf16 (tiled transpose via LDS)
__global__ __launch_bounds__(256) void k_cvt_wt(const float* __restrict__ W,
                                                u16* __restrict__ Wt) {
  __shared__ u16 tile[64][65];
  const int bc = blockIdx.x;
  const int tr0 = (bc >> 4) * 64;  // k
  const int tc0 = (bc & 15) * 64;  // n
  const int t = threadIdx.x;
  const int col = t & 63, rr = t >> 6;
#pragma unroll
  for (int p = 0; p < 16; ++p) {
    const int row = rr * 16 + p;
    tile[row][col] = f2bf(W[(size_t)(tr0 + row) * DOUT + tc0 + col]);
  }
  __syncthreads();
#pragma unroll
  for (int p = 0; p < 16; ++p) {
    const int row = rr * 16 + p;
    Wt[(size_t)(tc0 + row) * DIN + tr0 + col] = tile[col][row];
  }
}

// Fused QKV projection: Wt_all [3072][1024] (q|k|v). n0<2048 -> qk interleaved
// [16384][2048] row-major; n0>=2048 -> vT [b][d][s] transposed.
__global__ __launch_bounds__(256) void k_proj(const u16* __restrict__ xb,
                                              const u16* __restrict__ Wt,
                                              u16* __restrict__ qkb,
                                              u16* __restrict__ vT) {
  const int m0 = blockIdx.y * 128, n0 = blockIdx.x * 128;
  gemm_core(xb, DIN, Wt, DIN, m0, n0, DIN,
            [&](const f32x4(&acc)[4][4], int r0, int c0) {
              if (n0 < 2 * DOUT) {  // q or k: row-major into qkb
#pragma unroll
                for (int mi = 0; mi < 4; ++mi)
#pragma unroll
                  for (int nj = 0; nj < 4; ++nj) {
                    const int r = m0 + r0 + mi * 16;
                    const int c = n0 + c0 + nj * 16;
#pragma unroll
                    for (int i = 0; i < 4; ++i)
                      qkb[(size_t)(r + i) * 2048 + c] = f2bf(acc[mi][nj][i]);
                  }
              } else {  // v: transposed into vT[b][d][s]
                const int b = (m0 + r0) >> 11;
                const int sl = ((m0 + r0) & (CTX - 1));
                u16* C = vT + (size_t)b * DOUT * CTX;
#pragma unroll
                for (int mi = 0; mi < 4; ++mi)
#pragma unroll
                  for (int nj = 0; nj < 4; ++nj) {
                    const int d = n0 - 2 * DOUT + c0 + nj * 16;
                    const int s = sl + mi * 16;
                    ushort4 o;
                    o.x = f2bf(acc[mi][nj][0]);
                    o.y = f2bf(acc[mi][nj][1]);
                    o.z = f2bf(acc[mi][nj][2]);
                    o.w = f2bf(acc[mi][nj][3]);
                    *reinterpret_cast<ushort4*>(C + (size_t)d * CTX + s) = o;
                  }
              }
            });
}

// S[b][i][j] = (q.k)/32 for lower-triangular 128x128 tiles only
__global__ __launch_bounds__(256) void k_score(const u16* __restrict__ qkb,
                                               float* __restrict__ S) {
  const int u = blockIdx.x, b = blockIdx.y;
  int it = (int)((sqrtf(8.0f * u + 1.0f) - 1.0f) * 0.5f);
  while ((it + 1) * (it + 2) / 2 <= u) ++it;
  while (it * (it + 1) / 2 > u) --it;
  const int jt = u - it * (it + 1) / 2;
  const u16* Aq = qkb + (size_t)b * CTX * 2048;
  const u16* Bk = Aq + 1024;  // k columns
  float* C = S + ((size_t)b << 22);
  const int m0 = it * 128, n0 = jt * 128;
  gemm_core(Aq, 2048, Bk, 2048, m0, n0, DOUT,
            [&](const f32x4(&acc)[4][4], int r0, int c0) {
#pragma unroll
              for (int mi = 0; mi < 4; ++mi)
#pragma unroll
                for (int nj = 0; nj < 4; ++nj) {
                  const int r = m0 + r0 + mi * 16;
                  const int c = n0 + c0 + nj * 16;
#pragma unroll
                  for (int i = 0; i < 4; ++i)
                    C[(size_t)(r + i) * CTX + c] = acc[mi][nj][i] * 0.03125f;
                }
            });
}

// row softmax over S fp32, write P bf16 in place (row stride 8192B = 4096 u16),
// full 2048 cols written (zeros above diagonal) so PV GEMM needs no masking.
// Threads with j0 > i skip the load entirely (saves ~half the read traffic).
__global__ __launch_bounds__(256) void k_softmax(float* __restrict__ Sws) {
  const int row = blockIdx.x;
  const int b = row >> 11, i = row & (CTX - 1);
  const float* srow = Sws + ((size_t)b << 22) + ((size_t)i << 11);
  u16* prow = (u16*)(Sws + ((size_t)b << 22)) + ((size_t)i << 12);
  const int t = threadIdx.x;
  const int j0 = t * 8;
  float vv[8];
  if (j0 <= i) {
    const float4 v0 = *reinterpret_cast<const float4*>(srow + j0);
    const float4 v1 = *reinterpret_cast<const float4*>(srow + j0 + 4);
    vv[0] = v0.x; vv[1] = v0.y; vv[2] = v0.z; vv[3] = v0.w;
    vv[4] = v1.x; vv[5] = v1.y; vv[6] = v1.z; vv[7] = v1.w;
  } else {
#pragma unroll
    for (int p = 0; p < 8; ++p) vv[p] = -3.0e38f;
  }
  float mx = -3.0e38f;
#pragma unroll
  for (int p = 0; p < 8; ++p) {
    vv[p] = (j0 + p <= i) ? vv[p] : -3.0e38f;
    mx = fmaxf(mx, vv[p]);
  }
#pragma unroll
  for (int off = 32; off > 0; off >>= 1) mx = fmaxf(mx, __shfl_xor(mx, off));
  __shared__ float redm[4], reds[4];
  const int lane = t & 63, wid = t >> 6;
  if (lane == 0) redm[wid] = mx;
  __syncthreads();
  mx = fmaxf(fmaxf(redm[0], redm[1]), fmaxf(redm[2], redm[3]));
  float e[8], s = 0.f;
#pragma unroll
  for (int p = 0; p < 8; ++p) {
    e[p] = __expf(vv[p] - mx);
    s += e[p];
  }
#pragma unroll
  for (int off = 32; off > 0; off >>= 1) s += __shfl_xor(s, off);
  if (lane == 0) reds[wid] = s;
  __syncthreads();  // also orders: row reads above before in-place writes below
  s = reds[0] + reds[1] + reds[2] + reds[3];
  const float inv = 1.0f / s;
  ushort4 o0, o1;
  o0.x = (j0 + 0 <= i) ? f2bf(e[0] * inv) : (u16)0;
  o0.y = (j0 + 1 <= i) ? f2bf(e[1] * inv) : (u16)0;
  o0.z = (j0 + 2 <= i) ? f2bf(e[2] * inv) : (u16)0;
  o0.w = (j0 + 3 <= i) ? f2bf(e[3] * inv) : (u16)0;
  o1.x = (j0 + 4 <= i) ? f2bf(e[4] * inv) : (u16)0;
  o1.y = (j0 + 5 <= i) ? f2bf(e[5] * inv) : (u16)0;
  o1.z = (j0 + 6 <= i) ? f2bf(e[6] * inv) : (u16)0;
  o1.w = (j0 + 7 <= i) ? f2bf(e[7] * inv) : (u16)0;
  *reinterpret_cast<ushort4*>(prow + j0) = o0;
  *reinterpret_cast<ushort4*>(prow + j0 + 4) = o1;
}

// out[b][i][d] = sum_j P[b][i][j] * V[b][j][d]; K causally limited.
// LPT dispatch: it descending so the K=2048 blocks start first.
__global__ __launch_bounds__(256) void k_out(const float* __restrict__ Sws,
                                             const u16* __restrict__ vT,
                                             float* __restrict__ out) {
  const int idx = blockIdx.x;
  const int it = 15 - (idx >> 6);   // 15..0, long blocks dispatched first
  const int b = (idx >> 3) & 7;
  const int nt = idx & 7;
  const u16* P = (const u16*)(Sws + ((size_t)b << 22));  // lda = 4096 u16
  const u16* Bt = vT + (size_t)b * DOUT * CTX;           // [D][S]
  float* C = out + (size_t)b * CTX * DOUT;
  const int m0 = it * 128, n0 = nt * 128;
  gemm_core(P, 2 * CTX, Bt, CTX, m0, n0, (it + 1) * 128,
            [&](const f32x4(&acc)[4][4], int r0, int c0) {
#pragma unroll
              for (int mi = 0; mi < 4; ++mi)
#pragma unroll
                for (int nj = 0; nj < 4; ++nj) {
                  const int r = m0 + r0 + mi * 16;
                  const int c = n0 + c0 + nj * 16;
#pragma unroll
                  for (int i = 0; i < 4; ++i)
                    C[(size_t)(r + i) * DOUT + c] = acc[mi][nj][i];
                }
            });
}

// ---------------------------------------------------------------------------
extern "C" void kernel_launch(void* const* d_in, const int* in_sizes, int n_in,
                              void* d_out, int out_size, void* d_ws, size_t ws_size,
                              hipStream_t stream) {
  (void)in_sizes; (void)n_in; (void)out_size; (void)ws_size;
  const float* x = (const float*)d_in[0];
  const float* Wq = (const float*)d_in[1];
  const float* Wk = (const float*)d_in[2];
  const float* Wv = (const float*)d_in[3];
  float* out = (float*)d_out;
  uint8_t* ws = (uint8_t*)d_ws;

  // ws layout (224 MB):
  //   [0,128M): S fp32 [8][2048][2048] (P bf16 written in place by softmax)
  //     xb bf16 (32MB) + Wt_all (6MB) overlap S -- dead before k_score runs
  //   [128M,192M): qkb bf16 [8][2048][2048] (q cols 0..1023, k cols 1024..2047)
  //   [192M,224M): vT bf16 [8][1024][2048]
  float* S = (float*)ws;
  u16* xb = (u16*)ws;
  u16* Wt_all = (u16*)(ws + 33554432ull);  // [3072][1024]: q|k|v
  u16* qkb = (u16*)(ws + 134217728ull);
  u16* vT = (u16*)(ws + 201326592ull);

  k_cvt_x<<<16384, 256, 0, stream>>>(x, xb);
  k_cvt_wt<<<256, 256, 0, stream>>>(Wq, Wt_all);
  k_cvt_wt<<<256, 256, 0, stream>>>(Wk, Wt_all + 1024ull * 1024);
  k_cvt_wt<<<256, 256, 0, stream>>>(Wv, Wt_all + 2048ull * 1024);
  k_proj<<<dim3(3 * DOUT / 128, (NB * CTX) / 128), 256, 0, stream>>>(xb, Wt_all, qkb, vT);
  k_score<<<dim3(136, NB), 256, 0, stream>>>(qkb, S);
  k_softmax<<<NB * CTX, 256, 0, stream>>>(S);
  k_out<<<1024, 256, 0, stream>>>(S, vT, out);
}

// Round 4
// 330.073 us; speedup vs baseline: 1.5230x; 1.3177x over previous
//
#include <hip/hip_runtime.h>
#include <stdint.h>

typedef unsigned short u16;
typedef short bf16x8 __attribute__((ext_vector_type(8)));
typedef float f32x4 __attribute__((ext_vector_type(4)));

#define CTX 2048
#define DIN 1024
#define DOUT 1024
#define NB 8

__device__ __forceinline__ u16 f2bf(float f) {
  uint32_t u = __builtin_bit_cast(uint32_t, f);
  u += 0x7FFFu + ((u >> 16) & 1u);
  return (u16)(u >> 16);
}

// global -> LDS async, 16B per lane. LDS dest is wave-uniform base + lane*16.
__device__ __forceinline__ void gld_lds16(const u16* g, const u16* lds) {
  __builtin_amdgcn_global_load_lds(
      (const __attribute__((address_space(1))) uint32_t*)(unsigned long long)(const void*)g,
      (__attribute__((address_space(3))) uint32_t*)(uint32_t)(unsigned long long)(const void*)lds,
      16, 0, 0);
}

#define SBAR() asm volatile("s_barrier" ::: "memory")
#define VMCNT4() asm volatile("s_waitcnt vmcnt(4)" ::: "memory")
#define VMCNT0() asm volatile("s_waitcnt vmcnt(0)" ::: "memory")
#define SCHED0() __builtin_amdgcn_sched_barrier(0)

// ---------------------------------------------------------------------------
// 256x256-tile deep-pipelined GEMM: C = A[256xK] * Bt[256xK]^T, bf16, BK=64.
// 512 threads = 8 waves (2 m-halves x 4 n-cols); wave C = 128x64 = 8x4 frags.
// LDS: 2 bufs x 4 regions (A0,A1,B0,B1) x 16 blocks x 1KB = 128 KiB.
// Fragment-order LDS (block = fr*2+ks, lane-linear 16B) => both global_load_lds
// staging and ds_read_b128 are conflict-free by construction (no swizzle).
// Schedule per K-tile T (4 phases): P0 reads A fr0-3 + B nc0-1, stages B0(T+1);
// P1 reads A fr4-7, stages B1(T+1); P2 reads B nc2-3, stages A0(T+2);
// P3 stages A1(T+2), then boundary wait + barrier.
// Boundary ledger (steady state): 12 in flight; vmcnt(4) retires the 8 tile-
// (T+1) loads, leaves A(T+2). At T==nkt-2 the A-stage guard fired, only 8 in
// flight and 4 of them are B(nkt-1): must drain with vmcnt(0) there (the
// round-3 race: vmcnt(4) left B(nkt-1) in flight while tile nkt-1 read it).
// ---------------------------------------------------------------------------
template <typename EPI>
__device__ __forceinline__ void gemm256(const u16* __restrict__ A, int lda,
                                        const u16* __restrict__ Bt, int ldb,
                                        int m0, int n0, int K, EPI&& epi) {
  __shared__ __align__(16) u16 lds[65536];  // [buf2][region4][block16][512]

  const int t = threadIdx.x;
  const int lane = t & 63;
  const int w = t >> 6;     // 0..7
  const int wm = w >> 2;    // 0..1 (m half)
  const int wn = w & 3;     // 0..3 (n col group)
  const int l15 = lane & 15;
  const int l16 = lane >> 4;
  const int nkt = K >> 6;
  const int bf0 = (wn & 1) * 4;  // frag base within B region

  f32x4 acc[8][4];
#pragma unroll
  for (int i = 0; i < 8; ++i)
#pragma unroll
    for (int j = 0; j < 4; ++j) acc[i][j] = {0.f, 0.f, 0.f, 0.f};

  // per-thread global staging bases (wave w stages frag w; lane covers 16B)
  const u16* gA0 = A + (size_t)(m0 + w * 16 + l15) * lda + l16 * 8;
  const u16* gA1 = gA0 + (size_t)128 * lda;
  const u16* gB0 = Bt + (size_t)(n0 + w * 16 + l15) * ldb + l16 * 8;
  const u16* gB1 = gB0 + (size_t)128 * ldb;

  auto STAGEH = [&](int bb, int rr, const u16* g) {
    u16* d = lds + (((bb * 4 + rr) * 16) + w * 2) * 512;
    gld_lds16(g, d);             // kstep 0: cols +0..31
    gld_lds16(g + 32, d + 512);  // kstep 1: cols +32..63
  };

  // prologue: K-tile 0 fully + K-tile 1's A halves (mimics steady state)
  STAGEH(0, 0, gA0);
  STAGEH(0, 1, gA1);
  STAGEH(0, 2, gB0);
  STAGEH(0, 3, gB1);
  if (nkt > 1) {
    STAGEH(1, 0, gA0 + 64);
    STAGEH(1, 1, gA1 + 64);
  }
  VMCNT4();  // K-tile 0's 8 loads complete; K1-A's 4 in flight
  SBAR();

  bf16x8 ar[8][2], br[2][2];

  for (int T = 0; T < nkt; ++T) {
    const int b = T & 1;
    const u16* bufA = lds + ((b * 4 + wm) * 16) * 512 + lane * 8;
    const u16* bufB = lds + ((b * 4 + 2 + (wn >> 1)) * 16) * 512 + lane * 8;

    // ---- P0: read A fr0-3 + B nc0-1; stage B0(T+1)
#pragma unroll
    for (int fr = 0; fr < 4; ++fr)
#pragma unroll
      for (int ks = 0; ks < 2; ++ks)
        ar[fr][ks] = *reinterpret_cast<const bf16x8*>(bufA + (fr * 2 + ks) * 512);
#pragma unroll
    for (int nc = 0; nc < 2; ++nc)
#pragma unroll
      for (int ks = 0; ks < 2; ++ks)
        br[nc][ks] = *reinterpret_cast<const bf16x8*>(bufB + ((bf0 + nc) * 2 + ks) * 512);
    if (T + 1 < nkt) STAGEH(b ^ 1, 2, gB0 + (size_t)(T + 1) * 64);
    SBAR();
    SCHED0();
    __builtin_amdgcn_s_setprio(1);
#pragma unroll
    for (int fr = 0; fr < 4; ++fr)
#pragma unroll
      for (int nc = 0; nc < 2; ++nc)
#pragma unroll
        for (int ks = 0; ks < 2; ++ks)
          acc[fr][nc] = __builtin_amdgcn_mfma_f32_16x16x32_bf16(ar[fr][ks], br[nc][ks],
                                                                acc[fr][nc], 0, 0, 0);
    __builtin_amdgcn_s_setprio(0);
    SCHED0();
    SBAR();

    // ---- P1: read A fr4-7; stage B1(T+1)
#pragma unroll
    for (int fr = 4; fr < 8; ++fr)
#pragma unroll
      for (int ks = 0; ks < 2; ++ks)
        ar[fr][ks] = *reinterpret_cast<const bf16x8*>(bufA + (fr * 2 + ks) * 512);
    if (T + 1 < nkt) STAGEH(b ^ 1, 3, gB1 + (size_t)(T + 1) * 64);
    SBAR();
    SCHED0();
    __builtin_amdgcn_s_setprio(1);
#pragma unroll
    for (int fr = 4; fr < 8; ++fr)
#pragma unroll
      for (int nc = 0; nc < 2; ++nc)
#pragma unroll
        for (int ks = 0; ks < 2; ++ks)
          acc[fr][nc] = __builtin_amdgcn_mfma_f32_16x16x32_bf16(ar[fr][ks], br[nc][ks],
                                                                acc[fr][nc], 0, 0, 0);
    __builtin_amdgcn_s_setprio(0);
    SCHED0();
    SBAR();

    // ---- P2: read B nc2-3 (overwrite br); stage A0(T+2)
#pragma unroll
    for (int nc = 0; nc < 2; ++nc)
#pragma unroll
      for (int ks = 0; ks < 2; ++ks)
        br[nc][ks] = *reinterpret_cast<const bf16x8*>(bufB + ((bf0 + 2 + nc) * 2 + ks) * 512);
    if (T + 2 < nkt) STAGEH(b, 0, gA0 + (size_t)(T + 2) * 64);
    SBAR();
    SCHED0();
    __builtin_amdgcn_s_setprio(1);
#pragma unroll
    for (int fr = 0; fr < 4; ++fr)
#pragma unroll
      for (int nc = 0; nc < 2; ++nc)
#pragma unroll
        for (int ks = 0; ks < 2; ++ks)
          acc[fr][2 + nc] = __builtin_amdgcn_mfma_f32_16x16x32_bf16(ar[fr][ks], br[nc][ks],
                                                                    acc[fr][2 + nc], 0, 0, 0);
    __builtin_amdgcn_s_setprio(0);
    SCHED0();
    SBAR();

    // ---- P3: stage A1(T+2); MFMA fr4-7 x nc2-3; boundary wait
    if (T + 2 < nkt) STAGEH(b, 1, gA1 + (size_t)(T + 2) * 64);
    SBAR();
    SCHED0();
    __builtin_amdgcn_s_setprio(1);
#pragma unroll
    for (int fr = 4; fr < 8; ++fr)
#pragma unroll
      for (int nc = 0; nc < 2; ++nc)
#pragma unroll
        for (int ks = 0; ks < 2; ++ks)
          acc[fr][2 + nc] = __builtin_amdgcn_mfma_f32_16x16x32_bf16(ar[fr][ks], br[nc][ks],
                                                                    acc[fr][2 + nc], 0, 0, 0);
    __builtin_amdgcn_s_setprio(0);
    SCHED0();
    if (T + 2 < nkt) {
      VMCNT4();  // retires exactly tile T+1's 8 loads, leaves A(T+2)
    } else {
      VMCNT0();  // no A(T+2) staged: must fully drain so B(T+1) is landed
    }
    SBAR();
  }

  // epilogue: row = r0 + fr*16 + i, col = c0 + nc*16 (tile-local)
  epi(acc, wm * 128 + l16 * 4, wn * 64 + l15);
}

// ---------------------------------------------------------------------------
__global__ __launch_bounds__(256) void k_cvt_x(const float* __restrict__ x,
                                               u16* __restrict__ xb) {
  const int idx = (blockIdx.x * 256 + threadIdx.x) * 4;
  const float4 v = *reinterpret_cast<const float4*>(x + idx);
  ushort4 o;
  o.x = f2bf(v.x); o.y = f2bf(v.y); o.z = f2bf(v.z); o.w = f2bf(v.w);
  *reinterpret_cast<ushort4*>(xb + idx) = o;
}

// W [DIN][DOUT] fp32 -> Wt [DOUT][DIN] bf16 (tiled transpose via LDS)
__global__ __launch_bounds__(256) void k_cvt_wt(const float* __restrict__ W,
                                                u16* __restrict__ Wt) {
  __shared__ u16 tile[64][65];
  const int bc = blockIdx.x;
  const int tr0 = (bc >> 4) * 64;
  const int tc0 = (bc & 15) * 64;
  const int t = threadIdx.x;
  const int col = t & 63, rr = t >> 6;
#pragma unroll
  for (int p = 0; p < 16; ++p) {
    const int row = rr * 16 + p;
    tile[row][col] = f2bf(W[(size_t)(tr0 + row) * DOUT + tc0 + col]);
  }
  __syncthreads();
#pragma unroll
  for (int p = 0; p < 16; ++p) {
    const int row = rr * 16 + p;
    Wt[(size_t)(tc0 + row) * DIN + tr0 + col] = tile[col][row];
  }
}

// Fused QKV projection. 768 blocks, XCD-swizzled; n-tiles 0-7 -> qk row-major,
// 8-11 -> vT transposed.
__global__ __launch_bounds__(512, 2) void k_proj(const u16* __restrict__ xb,
                                                 const u16* __restrict__ Wt,
                                                 u16* __restrict__ qkb,
                                                 u16* __restrict__ vT) {
  const int wg = (blockIdx.x & 7) * 96 + (blockIdx.x >> 3);  // bijective, 768%8==0
  const int m0 = (wg / 12) * 256, n0 = (wg % 12) * 256;
  gemm256(xb, DIN, Wt, DIN, m0, n0, DIN,
          [&](const f32x4(&acc)[8][4], int r0, int c0) {
            if (n0 < 2 * DOUT) {  // q or k -> qkb row-major [16384][2048]
#pragma unroll
              for (int fr = 0; fr < 8; ++fr)
#pragma unroll
                for (int nc = 0; nc < 4; ++nc) {
                  const int r = m0 + r0 + fr * 16;
                  const int c = n0 + c0 + nc * 16;
#pragma unroll
                  for (int i = 0; i < 4; ++i)
                    qkb[(size_t)(r + i) * 2048 + c] = f2bf(acc[fr][nc][i]);
                }
            } else {  // v -> vT[b][d][s]
              const int b = m0 >> 11;
              const int sl = (m0 & (CTX - 1)) + r0;
              u16* C = vT + (size_t)b * DOUT * CTX;
#pragma unroll
              for (int fr = 0; fr < 8; ++fr)
#pragma unroll
                for (int nc = 0; nc < 4; ++nc) {
                  const int d = n0 - 2 * DOUT + c0 + nc * 16;
                  const int s = sl + fr * 16;
                  ushort4 o;
                  o.x = f2bf(acc[fr][nc][0]);
                  o.y = f2bf(acc[fr][nc][1]);
                  o.z = f2bf(acc[fr][nc][2]);
                  o.w = f2bf(acc[fr][nc][3]);
                  *reinterpret_cast<ushort4*>(C + (size_t)d * CTX + s) = o;
                }
            }
          });
}

// S[b][i][j] = (q.k)/32, lower-triangular 256x256 tiles (36 per batch)
__global__ __launch_bounds__(512, 2) void k_score(const u16* __restrict__ qkb,
                                                  float* __restrict__ S) {
  const int u = (blockIdx.x & 7) * 36 + (blockIdx.x >> 3);  // 288%8==0
  const int b = u / 36, v = u % 36;
  int it = 0;
  while ((it + 1) * (it + 2) / 2 <= v) ++it;
  const int jt = v - it * (it + 1) / 2;
  const u16* Aq = qkb + (size_t)b * CTX * 2048;
  float* C = S + ((size_t)b << 22);
  const int m0 = it * 256, n0 = jt * 256;
  gemm256(Aq, 2048, Aq + 1024, 2048, m0, n0, DOUT,
          [&](const f32x4(&acc)[8][4], int r0, int c0) {
#pragma unroll
            for (int fr = 0; fr < 8; ++fr)
#pragma unroll
              for (int nc = 0; nc < 4; ++nc) {
                const int r = m0 + r0 + fr * 16;
                const int c = n0 + c0 + nc * 16;
#pragma unroll
                for (int i = 0; i < 4; ++i)
                  C[(size_t)(r + i) * CTX + c] = acc[fr][nc][i] * 0.03125f;
              }
          });
}

// row softmax over S fp32, write P bf16 in place (row stride 4096 u16),
// full 2048 cols written (zeros above diagonal) so PV GEMM needs no masking.
__global__ __launch_bounds__(256) void k_softmax(float* __restrict__ Sws) {
  const int row = blockIdx.x;
  const int b = row >> 11, i = row & (CTX - 1);
  const float* srow = Sws + ((size_t)b << 22) + ((size_t)i << 11);
  u16* prow = (u16*)(Sws + ((size_t)b << 22)) + ((size_t)i << 12);
  const int t = threadIdx.x;
  const int j0 = t * 8;
  float vv[8];
  if (j0 <= i) {
    const float4 v0 = *reinterpret_cast<const float4*>(srow + j0);
    const float4 v1 = *reinterpret_cast<const float4*>(srow + j0 + 4);
    vv[0] = v0.x; vv[1] = v0.y; vv[2] = v0.z; vv[3] = v0.w;
    vv[4] = v1.x; vv[5] = v1.y; vv[6] = v1.z; vv[7] = v1.w;
  } else {
#pragma unroll
    for (int p = 0; p < 8; ++p) vv[p] = -3.0e38f;
  }
  float mx = -3.0e38f;
#pragma unroll
  for (int p = 0; p < 8; ++p) {
    vv[p] = (j0 + p <= i) ? vv[p] : -3.0e38f;
    mx = fmaxf(mx, vv[p]);
  }
#pragma unroll
  for (int off = 32; off > 0; off >>= 1) mx = fmaxf(mx, __shfl_xor(mx, off));
  __shared__ float redm[4], reds[4];
  const int lane = t & 63, wid = t >> 6;
  if (lane == 0) redm[wid] = mx;
  __syncthreads();
  mx = fmaxf(fmaxf(redm[0], redm[1]), fmaxf(redm[2], redm[3]));
  float e[8], s = 0.f;
#pragma unroll
  for (int p = 0; p < 8; ++p) {
    e[p] = __expf(vv[p] - mx);
    s += e[p];
  }
#pragma unroll
  for (int off = 32; off > 0; off >>= 1) s += __shfl_xor(s, off);
  if (lane == 0) reds[wid] = s;
  __syncthreads();  // orders row reads above before in-place writes below
  s = reds[0] + reds[1] + reds[2] + reds[3];
  const float inv = 1.0f / s;
  ushort4 o0, o1;
  o0.x = (j0 + 0 <= i) ? f2bf(e[0] * inv) : (u16)0;
  o0.y = (j0 + 1 <= i) ? f2bf(e[1] * inv) : (u16)0;
  o0.z = (j0 + 2 <= i) ? f2bf(e[2] * inv) : (u16)0;
  o0.w = (j0 + 3 <= i) ? f2bf(e[3] * inv) : (u16)0;
  o1.x = (j0 + 4 <= i) ? f2bf(e[4] * inv) : (u16)0;
  o1.y = (j0 + 5 <= i) ? f2bf(e[5] * inv) : (u16)0;
  o1.z = (j0 + 6 <= i) ? f2bf(e[6] * inv) : (u16)0;
  o1.w = (j0 + 7 <= i) ? f2bf(e[7] * inv) : (u16)0;
  *reinterpret_cast<ushort4*>(prow + j0) = o0;
  *reinterpret_cast<ushort4*>(prow + j0 + 4) = o1;
}

// out[b][i][d] = sum_j P[b][i][j] * V[b][j][d]; K causally limited; LPT order.
__global__ __launch_bounds__(512, 2) void k_out(const float* __restrict__ Sws,
                                                const u16* __restrict__ vT,
                                                float* __restrict__ out) {
  const int idx = blockIdx.x;          // 256 blocks = 8it x 8b x 4nt
  const int it = 7 - (idx >> 5);       // longest (K=2048) first
  const int b = (idx >> 2) & 7;
  const int nt = idx & 3;
  const u16* P = (const u16*)(Sws + ((size_t)b << 22));  // lda = 4096 u16
  const u16* Bt = vT + (size_t)b * DOUT * CTX;           // [D][S]
  float* C = out + (size_t)b * CTX * DOUT;
  const int m0 = it * 256, n0 = nt * 256;
  gemm256(P, 2 * CTX, Bt, CTX, m0, n0, (it + 1) * 256,
          [&](const f32x4(&acc)[8][4], int r0, int c0) {
#pragma unroll
            for (int fr = 0; fr < 8; ++fr)
#pragma unroll
              for (int nc = 0; nc < 4; ++nc) {
                const int r = m0 + r0 + fr * 16;
                const int c = n0 + c0 + nc * 16;
#pragma unroll
                for (int i = 0; i < 4; ++i)
                  C[(size_t)(r + i) * DOUT + c] = acc[fr][nc][i];
              }
          });
}

// ---------------------------------------------------------------------------
extern "C" void kernel_launch(void* const* d_in, const int* in_sizes, int n_in,
                              void* d_out, int out_size, void* d_ws, size_t ws_size,
                              hipStream_t stream) {
  (void)in_sizes; (void)n_in; (void)out_size; (void)ws_size;
  const float* x = (const float*)d_in[0];
  const float* Wq = (const float*)d_in[1];
  const float* Wk = (const float*)d_in[2];
  const float* Wv = (const float*)d_in[3];
  float* out = (float*)d_out;
  uint8_t* ws = (uint8_t*)d_ws;

  // ws layout (224 MB):
  //   [0,128M): S fp32 [8][2048][2048] (P bf16 written in place by softmax)
  //     xb bf16 (32MB) + Wt_all (6MB) overlap S -- dead before k_score runs
  //   [128M,192M): qkb bf16 [8][2048][2048] (q cols 0..1023, k cols 1024..2047)
  //   [192M,224M): vT bf16 [8][1024][2048]
  float* S = (float*)ws;
  u16* xb = (u16*)ws;
  u16* Wt_all = (u16*)(ws + 33554432ull);  // [3072][1024]: q|k|v
  u16* qkb = (u16*)(ws + 134217728ull);
  u16* vT = (u16*)(ws + 201326592ull);

  k_cvt_x<<<16384, 256, 0, stream>>>(x, xb);
  k_cvt_wt<<<256, 256, 0, stream>>>(Wq, Wt_all);
  k_cvt_wt<<<256, 256, 0, stream>>>(Wk, Wt_all + 1024ull * 1024);
  k_cvt_wt<<<256, 256, 0, stream>>>(Wv, Wt_all + 2048ull * 1024);
  k_proj<<<768, 512, 0, stream>>>(xb, Wt_all, qkb, vT);
  k_score<<<288, 512, 0, stream>>>(qkb, S);
  k_softmax<<<NB * CTX, 256, 0, stream>>>(S);
  k_out<<<256, 512, 0, stream>>>(S, vT, out);
}

// Round 5
// 312.410 us; speedup vs baseline: 1.6091x; 1.0565x over previous
//
#include <hip/hip_runtime.h>
#include <stdint.h>

typedef unsigned short u16;
typedef short bf16x8 __attribute__((ext_vector_type(8)));
typedef float f32x4 __attribute__((ext_vector_type(4)));

#define CTX 2048
#define DIN 1024
#define DOUT 1024
#define NB 8

__device__ __forceinline__ u16 f2bf(float f) {
  uint32_t u = __builtin_bit_cast(uint32_t, f);
  u += 0x7FFFu + ((u >> 16) & 1u);
  return (u16)(u >> 16);
}

// global -> LDS async, 16B per lane. LDS dest is wave-uniform base + lane*16.
__device__ __forceinline__ void gld_lds16(const u16* g, const u16* lds) {
  __builtin_amdgcn_global_load_lds(
      (const __attribute__((address_space(1))) uint32_t*)(unsigned long long)(const void*)g,
      (__attribute__((address_space(3))) uint32_t*)(uint32_t)(unsigned long long)(const void*)lds,
      16, 0, 0);
}

#define SBAR() asm volatile("s_barrier" ::: "memory")
#define VMCNT4() asm volatile("s_waitcnt vmcnt(4)" ::: "memory")
#define VMCNT0() asm volatile("s_waitcnt vmcnt(0)" ::: "memory")
#define SCHED0() __builtin_amdgcn_sched_barrier(0)

// ---------------------------------------------------------------------------
// 256x256-tile deep-pipelined GEMM, bf16, BK=64, 512 thr = 8 waves (2Mx4N).
// ROTATED schedule (round 5): each barrier region = {stage; MFMA(operands
// loaded in PREVIOUS region); ds_reads(operands for NEXT region); bar} so the
// DS pipe and VMEM issue overlap the matrix pipe instead of alternating with
// it. 4 barriers/K-tile (was 8).
// Register sets: arLo(fr0-3), arHi(fr4-7), one br set alternating brA/brB
// roles (reads are placed AFTER the cluster consuming the old contents; WAR
// is interlocked by HW). Cluster order per tile: C0=Lo*brA, C1=Hi*brA,
// C2=Hi*brB, C3=Lo*brB (C3 runs in the next tile's first region).
// Stage schedule per iter T: P1:B1(T+1); P2:A0(T+2); P3:A1(T+2); P0':B0(T+2).
// vmcnt ledger (induction, steady state): at P3(T) boundary 12 in flight,
// vmcnt(4) retires tile-(T+1)'s 8, leaves A(T+2). When T+2>=nkt the A/B
// stages were skipped: 8 in flight, all tile-(T+1) -> vmcnt(0).
// Requires nkt >= 2 (all call sites have nkt >= 4).
// ---------------------------------------------------------------------------
template <typename EPI>
__device__ __forceinline__ void gemm256(const u16* __restrict__ A, int lda,
                                        const u16* __restrict__ Bt, int ldb,
                                        int m0, int n0, int K, EPI&& epi) {
  __shared__ __align__(16) u16 lds[65536];  // [buf2][region4][block16][512]

  const int t = threadIdx.x;
  const int lane = t & 63;
  const int w = t >> 6;     // 0..7
  const int wm = w >> 2;    // 0..1 (m half)
  const int wn = w & 3;     // 0..3 (n col group)
  const int l15 = lane & 15;
  const int l16 = lane >> 4;
  const int nkt = K >> 6;
  const int bf0 = (wn & 1) * 4;  // frag base within B region

  f32x4 acc[8][4];
#pragma unroll
  for (int i = 0; i < 8; ++i)
#pragma unroll
    for (int j = 0; j < 4; ++j) acc[i][j] = {0.f, 0.f, 0.f, 0.f};

  const u16* gA0 = A + (size_t)(m0 + w * 16 + l15) * lda + l16 * 8;
  const u16* gA1 = gA0 + (size_t)128 * lda;
  const u16* gB0 = Bt + (size_t)(n0 + w * 16 + l15) * ldb + l16 * 8;
  const u16* gB1 = gB0 + (size_t)128 * ldb;

  auto STAGEH = [&](int bb, int rr, const u16* g) {
    u16* d = lds + (((bb * 4 + rr) * 16) + w * 2) * 512;
    gld_lds16(g, d);             // kstep 0: cols +0..31
    gld_lds16(g + 32, d + 512);  // kstep 1: cols +32..63
  };

  // prologue: tile 0 fully + tile 1's A halves
  STAGEH(0, 0, gA0);
  STAGEH(0, 1, gA1);
  STAGEH(0, 2, gB0);
  STAGEH(0, 3, gB1);
  if (nkt > 1) {
    STAGEH(1, 0, gA0 + 64);
    STAGEH(1, 1, gA1 + 64);
  }
  VMCNT4();  // tile 0's 8 loads landed; tile-1-A's 4 in flight
  SBAR();

  bf16x8 arLo[4][2], arHi[4][2], br[2][2];

  // pre-loop region P0(0): stage B0(1); read arLo(0), brA(0)
  {
    if (1 < nkt) STAGEH(1, 2, gB0 + 64);
    const u16* bufA = lds + ((0 * 4 + wm) * 16) * 512 + lane * 8;
    const u16* bufB = lds + ((0 * 4 + 2 + (wn >> 1)) * 16) * 512 + lane * 8;
#pragma unroll
    for (int fr = 0; fr < 4; ++fr)
#pragma unroll
      for (int ks = 0; ks < 2; ++ks)
        arLo[fr][ks] = *reinterpret_cast<const bf16x8*>(bufA + (fr * 2 + ks) * 512);
#pragma unroll
    for (int nc = 0; nc < 2; ++nc)
#pragma unroll
      for (int ks = 0; ks < 2; ++ks)
        br[nc][ks] = *reinterpret_cast<const bf16x8*>(bufB + ((bf0 + nc) * 2 + ks) * 512);
    SBAR();
  }

  for (int T = 0; T < nkt; ++T) {
    const int b = T & 1;
    const u16* bufA = lds + ((b * 4 + wm) * 16) * 512 + lane * 8;
    const u16* bufB = lds + ((b * 4 + 2 + (wn >> 1)) * 16) * 512 + lane * 8;
    const u16* bufAn = lds + (((b ^ 1) * 4 + wm) * 16) * 512 + lane * 8;
    const u16* bufBn = lds + (((b ^ 1) * 4 + 2 + (wn >> 1)) * 16) * 512 + lane * 8;

    // ---- P1: stage B1(T+1); MFMA C0 = arLo x brA; read arHi(T); bar
    if (T + 1 < nkt) STAGEH(b ^ 1, 3, gB1 + (size_t)(T + 1) * 64);
    SCHED0();
    __builtin_amdgcn_s_setprio(1);
#pragma unroll
    for (int fr = 0; fr < 4; ++fr)
#pragma unroll
      for (int nc = 0; nc < 2; ++nc)
#pragma unroll
        for (int ks = 0; ks < 2; ++ks)
          acc[fr][nc] = __builtin_amdgcn_mfma_f32_16x16x32_bf16(arLo[fr][ks], br[nc][ks],
                                                                acc[fr][nc], 0, 0, 0);
    __builtin_amdgcn_s_setprio(0);
    SCHED0();
#pragma unroll
    for (int fr = 0; fr < 4; ++fr)
#pragma unroll
      for (int ks = 0; ks < 2; ++ks)
        arHi[fr][ks] = *reinterpret_cast<const bf16x8*>(bufA + ((fr + 4) * 2 + ks) * 512);
    SBAR();

    // ---- P2: stage A0(T+2); MFMA C1 = arHi x brA; read brB(T) into br; bar
    if (T + 2 < nkt) STAGEH(b, 0, gA0 + (size_t)(T + 2) * 64);
    SCHED0();
    __builtin_amdgcn_s_setprio(1);
#pragma unroll
    for (int fr = 0; fr < 4; ++fr)
#pragma unroll
      for (int nc = 0; nc < 2; ++nc)
#pragma unroll
        for (int ks = 0; ks < 2; ++ks)
          acc[4 + fr][nc] = __builtin_amdgcn_mfma_f32_16x16x32_bf16(arHi[fr][ks], br[nc][ks],
                                                                    acc[4 + fr][nc], 0, 0, 0);
    __builtin_amdgcn_s_setprio(0);
    SCHED0();
#pragma unroll
    for (int nc = 0; nc < 2; ++nc)
#pragma unroll
      for (int ks = 0; ks < 2; ++ks)
        br[nc][ks] = *reinterpret_cast<const bf16x8*>(bufB + ((bf0 + 2 + nc) * 2 + ks) * 512);
    SBAR();

    // ---- P3: stage A1(T+2); MFMA C2 = arHi x brB; boundary vmcnt; bar
    if (T + 2 < nkt) STAGEH(b, 1, gA1 + (size_t)(T + 2) * 64);
    SCHED0();
    __builtin_amdgcn_s_setprio(1);
#pragma unroll
    for (int fr = 0; fr < 4; ++fr)
#pragma unroll
      for (int nc = 0; nc < 2; ++nc)
#pragma unroll
        for (int ks = 0; ks < 2; ++ks)
          acc[4 + fr][2 + nc] = __builtin_amdgcn_mfma_f32_16x16x32_bf16(arHi[fr][ks], br[nc][ks],
                                                                        acc[4 + fr][2 + nc], 0, 0, 0);
    __builtin_amdgcn_s_setprio(0);
    SCHED0();
    if (T + 2 < nkt) {
      VMCNT4();  // retires tile-(T+1)'s 8 loads, leaves A(T+2)
    } else {
      VMCNT0();  // no A(T+2) staged: drain so tile T+1 (if any) is landed
    }
    SBAR();

    // ---- P0(T+1): stage B0(T+2); MFMA C3 = arLo x brB; read arLo/brA(T+1); bar
    if (T + 2 < nkt) STAGEH(b, 2, gB0 + (size_t)(T + 2) * 64);
    SCHED0();
    __builtin_amdgcn_s_setprio(1);
#pragma unroll
    for (int fr = 0; fr < 4; ++fr)
#pragma unroll
      for (int nc = 0; nc < 2; ++nc)
#pragma unroll
        for (int ks = 0; ks < 2; ++ks)
          acc[fr][2 + nc] = __builtin_amdgcn_mfma_f32_16x16x32_bf16(arLo[fr][ks], br[nc][ks],
                                                                    acc[fr][2 + nc], 0, 0, 0);
    __builtin_amdgcn_s_setprio(0);
    SCHED0();
    if (T + 1 < nkt) {
#pragma unroll
      for (int fr = 0; fr < 4; ++fr)
#pragma unroll
        for (int ks = 0; ks < 2; ++ks)
          arLo[fr][ks] = *reinterpret_cast<const bf16x8*>(bufAn + (fr * 2 + ks) * 512);
#pragma unroll
      for (int nc = 0; nc < 2; ++nc)
#pragma unroll
        for (int ks = 0; ks < 2; ++ks)
          br[nc][ks] = *reinterpret_cast<const bf16x8*>(bufBn + ((bf0 + nc) * 2 + ks) * 512);
    }
    SBAR();
  }

  // epilogue: row = r0 + fr*16 + i, col = c0 + nc*16 (tile-local)
  epi(acc, wm * 128 + l16 * 4, wn * 64 + l15);
}

// ---------------------------------------------------------------------------
__global__ __launch_bounds__(256) void k_cvt_x(const float* __restrict__ x,
                                               u16* __restrict__ xb) {
  const int idx = (blockIdx.x * 256 + threadIdx.x) * 4;
  const float4 v = *reinterpret_cast<const float4*>(x + idx);
  ushort4 o;
  o.x = f2bf(v.x); o.y = f2bf(v.y); o.z = f2bf(v.z); o.w = f2bf(v.w);
  *reinterpret_cast<ushort4*>(xb + idx) = o;
}

// W [DIN][DOUT] fp32 -> Wt [DOUT][DIN] bf16 (tiled transpose via LDS)
__global__ __launch_bounds__(256) void k_cvt_wt(const float* __restrict__ W,
                                                u16* __restrict__ Wt) {
  __shared__ u16 tile[64][65];
  const int bc = blockIdx.x;
  const int tr0 = (bc >> 4) * 64;
  const int tc0 = (bc & 15) * 64;
  const int t = threadIdx.x;
  const int col = t & 63, rr = t >> 6;
#pragma unroll
  for (int p = 0; p < 16; ++p) {
    const int row = rr * 16 + p;
    tile[row][col] = f2bf(W[(size_t)(tr0 + row) * DOUT + tc0 + col]);
  }
  __syncthreads();
#pragma unroll
  for (int p = 0; p < 16; ++p) {
    const int row = rr * 16 + p;
    Wt[(size_t)(tc0 + row) * DIN + tr0 + col] = tile[col][row];
  }
}

// Fused QKV projection. 768 blocks, XCD-swizzled; n-tiles 0-7 -> qk row-major,
// 8-11 -> vT transposed.
__global__ __launch_bounds__(512, 2) void k_proj(const u16* __restrict__ xb,
                                                 const u16* __restrict__ Wt,
                                                 u16* __restrict__ qkb,
                                                 u16* __restrict__ vT) {
  const int wg = (blockIdx.x & 7) * 96 + (blockIdx.x >> 3);  // bijective, 768%8==0
  const int m0 = (wg / 12) * 256, n0 = (wg % 12) * 256;
  gemm256(xb, DIN, Wt, DIN, m0, n0, DIN,
          [&](const f32x4(&acc)[8][4], int r0, int c0) {
            if (n0 < 2 * DOUT) {  // q or k -> qkb row-major [16384][2048]
#pragma unroll
              for (int fr = 0; fr < 8; ++fr)
#pragma unroll
                for (int nc = 0; nc < 4; ++nc) {
                  const int r = m0 + r0 + fr * 16;
                  const int c = n0 + c0 + nc * 16;
#pragma unroll
                  for (int i = 0; i < 4; ++i)
                    qkb[(size_t)(r + i) * 2048 + c] = f2bf(acc[fr][nc][i]);
                }
            } else {  // v -> vT[b][d][s]
              const int b = m0 >> 11;
              const int sl = (m0 & (CTX - 1)) + r0;
              u16* C = vT + (size_t)b * DOUT * CTX;
#pragma unroll
              for (int fr = 0; fr < 8; ++fr)
#pragma unroll
                for (int nc = 0; nc < 4; ++nc) {
                  const int d = n0 - 2 * DOUT + c0 + nc * 16;
                  const int s = sl + fr * 16;
                  ushort4 o;
                  o.x = f2bf(acc[fr][nc][0]);
                  o.y = f2bf(acc[fr][nc][1]);
                  o.z = f2bf(acc[fr][nc][2]);
                  o.w = f2bf(acc[fr][nc][3]);
                  *reinterpret_cast<ushort4*>(C + (size_t)d * CTX + s) = o;
                }
            }
          });
}

// S[b][i][j] = (q.k)/32, lower-triangular 256x256 tiles (36 per batch)
__global__ __launch_bounds__(512, 2) void k_score(const u16* __restrict__ qkb,
                                                  float* __restrict__ S) {
  const int u = (blockIdx.x & 7) * 36 + (blockIdx.x >> 3);  // 288%8==0
  const int b = u / 36, v = u % 36;
  int it = 0;
  while ((it + 1) * (it + 2) / 2 <= v) ++it;
  const int jt = v - it * (it + 1) / 2;
  const u16* Aq = qkb + (size_t)b * CTX * 2048;
  float* C = S + ((size_t)b << 22);
  const int m0 = it * 256, n0 = jt * 256;
  gemm256(Aq, 2048, Aq + 1024, 2048, m0, n0, DOUT,
          [&](const f32x4(&acc)[8][4], int r0, int c0) {
#pragma unroll
            for (int fr = 0; fr < 8; ++fr)
#pragma unroll
              for (int nc = 0; nc < 4; ++nc) {
                const int r = m0 + r0 + fr * 16;
                const int c = n0 + c0 + nc * 16;
#pragma unroll
                for (int i = 0; i < 4; ++i)
                  C[(size_t)(r + i) * CTX + c] = acc[fr][nc][i] * 0.03125f;
              }
          });
}

// row softmax over S fp32, write P bf16 in place (row stride 4096 u16),
// full 2048 cols written (zeros above diagonal) so PV GEMM needs no masking.
__global__ __launch_bounds__(256) void k_softmax(float* __restrict__ Sws) {
  const int row = blockIdx.x;
  const int b = row >> 11, i = row & (CTX - 1);
  const float* srow = Sws + ((size_t)b << 22) + ((size_t)i << 11);
  u16* prow = (u16*)(Sws + ((size_t)b << 22)) + ((size_t)i << 12);
  const int t = threadIdx.x;
  const int j0 = t * 8;
  float vv[8];
  if (j0 <= i) {
    const float4 v0 = *reinterpret_cast<const float4*>(srow + j0);
    const float4 v1 = *reinterpret_cast<const float4*>(srow + j0 + 4);
    vv[0] = v0.x; vv[1] = v0.y; vv[2] = v0.z; vv[3] = v0.w;
    vv[4] = v1.x; vv[5] = v1.y; vv[6] = v1.z; vv[7] = v1.w;
  } else {
#pragma unroll
    for (int p = 0; p < 8; ++p) vv[p] = -3.0e38f;
  }
  float mx = -3.0e38f;
#pragma unroll
  for (int p = 0; p < 8; ++p) {
    vv[p] = (j0 + p <= i) ? vv[p] : -3.0e38f;
    mx = fmaxf(mx, vv[p]);
  }
#pragma unroll
  for (int off = 32; off > 0; off >>= 1) mx = fmaxf(mx, __shfl_xor(mx, off));
  __shared__ float redm[4], reds[4];
  const int lane = t & 63, wid = t >> 6;
  if (lane == 0) redm[wid] = mx;
  __syncthreads();
  mx = fmaxf(fmaxf(redm[0], redm[1]), fmaxf(redm[2], redm[3]));
  float e[8], s = 0.f;
#pragma unroll
  for (int p = 0; p < 8; ++p) {
    e[p] = __expf(vv[p] - mx);
    s += e[p];
  }
#pragma unroll
  for (int off = 32; off > 0; off >>= 1) s += __shfl_xor(s, off);
  if (lane == 0) reds[wid] = s;
  __syncthreads();  // orders row reads above before in-place writes below
  s = reds[0] + reds[1] + reds[2] + reds[3];
  const float inv = 1.0f / s;
  ushort4 o0, o1;
  o0.x = (j0 + 0 <= i) ? f2bf(e[0] * inv) : (u16)0;
  o0.y = (j0 + 1 <= i) ? f2bf(e[1] * inv) : (u16)0;
  o0.z = (j0 + 2 <= i) ? f2bf(e[2] * inv) : (u16)0;
  o0.w = (j0 + 3 <= i) ? f2bf(e[3] * inv) : (u16)0;
  o1.x = (j0 + 4 <= i) ? f2bf(e[4] * inv) : (u16)0;
  o1.y = (j0 + 5 <= i) ? f2bf(e[5] * inv) : (u16)0;
  o1.z = (j0 + 6 <= i) ? f2bf(e[6] * inv) : (u16)0;
  o1.w = (j0 + 7 <= i) ? f2bf(e[7] * inv) : (u16)0;
  *reinterpret_cast<ushort4*>(prow + j0) = o0;
  *reinterpret_cast<ushort4*>(prow + j0 + 4) = o1;
}

// out[b][i][d] = sum_j P[b][i][j] * V[b][j][d]; K causally limited; LPT order.
__global__ __launch_bounds__(512, 2) void k_out(const float* __restrict__ Sws,
                                                const u16* __restrict__ vT,
                                                float* __restrict__ out) {
  const int idx = blockIdx.x;          // 256 blocks = 8it x 8b x 4nt
  const int it = 7 - (idx >> 5);       // longest (K=2048) first
  const int b = (idx >> 2) & 7;
  const int nt = idx & 3;
  const u16* P = (const u16*)(Sws + ((size_t)b << 22));  // lda = 4096 u16
  const u16* Bt = vT + (size_t)b * DOUT * CTX;           // [D][S]
  float* C = out + (size_t)b * CTX * DOUT;
  const int m0 = it * 256, n0 = nt * 256;
  gemm256(P, 2 * CTX, Bt, CTX, m0, n0, (it + 1) * 256,
          [&](const f32x4(&acc)[8][4], int r0, int c0) {
#pragma unroll
            for (int fr = 0; fr < 8; ++fr)
#pragma unroll
              for (int nc = 0; nc < 4; ++nc) {
                const int r = m0 + r0 + fr * 16;
                const int c = n0 + c0 + nc * 16;
#pragma unroll
                for (int i = 0; i < 4; ++i)
                  C[(size_t)(r + i) * DOUT + c] = acc[fr][nc][i];
              }
          });
}

// ---------------------------------------------------------------------------
extern "C" void kernel_launch(void* const* d_in, const int* in_sizes, int n_in,
                              void* d_out, int out_size, void* d_ws, size_t ws_size,
                              hipStream_t stream) {
  (void)in_sizes; (void)n_in; (void)out_size; (void)ws_size;
  const float* x = (const float*)d_in[0];
  const float* Wq = (const float*)d_in[1];
  const float* Wk = (const float*)d_in[2];
  const float* Wv = (const float*)d_in[3];
  float* out = (float*)d_out;
  uint8_t* ws = (uint8_t*)d_ws;

  // ws layout (224 MB):
  //   [0,128M): S fp32 [8][2048][2048] (P bf16 written in place by softmax)
  //     xb bf16 (32MB) + Wt_all (6MB) overlap S -- dead before k_score runs
  //   [128M,192M): qkb bf16 [8][2048][2048] (q cols 0..1023, k cols 1024..2047)
  //   [192M,224M): vT bf16 [8][1024][2048]
  float* S = (float*)ws;
  u16* xb = (u16*)ws;
  u16* Wt_all = (u16*)(ws + 33554432ull);  // [3072][1024]: q|k|v
  u16* qkb = (u16*)(ws + 134217728ull);
  u16* vT = (u16*)(ws + 201326592ull);

  k_cvt_x<<<16384, 256, 0, stream>>>(x, xb);
  k_cvt_wt<<<256, 256, 0, stream>>>(Wq, Wt_all);
  k_cvt_wt<<<256, 256, 0, stream>>>(Wk, Wt_all + 1024ull * 1024);
  k_cvt_wt<<<256, 256, 0, stream>>>(Wv, Wt_all + 2048ull * 1024);
  k_proj<<<768, 512, 0, stream>>>(xb, Wt_all, qkb, vT);
  k_score<<<288, 512, 0, stream>>>(qkb, S);
  k_softmax<<<NB * CTX, 256, 0, stream>>>(S);
  k_out<<<256, 512, 0, stream>>>(S, vT, out);
}

// Round 6
// 311.800 us; speedup vs baseline: 1.6123x; 1.0020x over previous
//
#include <hip/hip_runtime.h>
#include <stdint.h>

typedef unsigned short u16;
typedef short bf16x8 __attribute__((ext_vector_type(8)));
typedef float f32x4 __attribute__((ext_vector_type(4)));

#define CTX 2048
#define DIN 1024
#define DOUT 1024
#define NB 8

__device__ __forceinline__ u16 f2bf(float f) {
  uint32_t u = __builtin_bit_cast(uint32_t, f);
  u += 0x7FFFu + ((u >> 16) & 1u);
  return (u16)(u >> 16);
}

// global -> LDS async, 16B per lane. LDS dest is wave-uniform base + lane*16.
__device__ __forceinline__ void gld_lds16(const u16* g, const u16* lds) {
  __builtin_amdgcn_global_load_lds(
      (const __attribute__((address_space(1))) uint32_t*)(unsigned long long)(const void*)g,
      (__attribute__((address_space(3))) uint32_t*)(uint32_t)(unsigned long long)(const void*)lds,
      16, 0, 0);
}

#define SBAR() asm volatile("s_barrier" ::: "memory")
#define VMCNT4() asm volatile("s_waitcnt vmcnt(4)" ::: "memory")
#define VMCNT0() asm volatile("s_waitcnt vmcnt(0)" ::: "memory")

// ---------------------------------------------------------------------------
// 256x256-tile deep-pipelined GEMM, bf16, BK=64, 512 thr = 8 waves (2Mx4N).
// Rotated schedule (round 5) MINUS sched_barrier pinning (round 6): each
// barrier region = {stage; MFMA(operands from PREVIOUS region); ds_reads(for
// NEXT region)} with the compiler free to interleave DS/VMEM issue into the
// MFMA cluster (m196: the fine interleave is the lever). Correctness: the
// "memory"-clobbered s_barrier / s_waitcnt asm still order all LDS/VMEM ops;
// the vmcnt ledger is unchanged from the round-4-verified one:
//   steady state 12 in flight at P3(T) boundary; vmcnt(4) retires tile-(T+1)'s
//   8, leaves A(T+2)'s 4. When T+2>=nkt: 8 in flight, all tile-(T+1) ->
//   vmcnt(0). K-loop unrolled x2 (nkt even at all call sites; nkt >= 4).
// ---------------------------------------------------------------------------
template <typename EPI>
__device__ __forceinline__ void gemm256(const u16* __restrict__ A, int lda,
                                        const u16* __restrict__ Bt, int ldb,
                                        int m0, int n0, int K, EPI&& epi) {
  __shared__ __align__(16) u16 lds[65536];  // [buf2][region4][block16][512]

  const int t = threadIdx.x;
  const int lane = t & 63;
  const int w = t >> 6;     // 0..7
  const int wm = w >> 2;    // 0..1 (m half)
  const int wn = w & 3;     // 0..3 (n col group)
  const int l15 = lane & 15;
  const int l16 = lane >> 4;
  const int nkt = K >> 6;
  const int bf0 = (wn & 1) * 4;  // frag base within B region

  f32x4 acc[8][4];
#pragma unroll
  for (int i = 0; i < 8; ++i)
#pragma unroll
    for (int j = 0; j < 4; ++j) acc[i][j] = {0.f, 0.f, 0.f, 0.f};

  const u16* gA0 = A + (size_t)(m0 + w * 16 + l15) * lda + l16 * 8;
  const u16* gA1 = gA0 + (size_t)128 * lda;
  const u16* gB0 = Bt + (size_t)(n0 + w * 16 + l15) * ldb + l16 * 8;
  const u16* gB1 = gB0 + (size_t)128 * ldb;

  auto STAGEH = [&](int bb, int rr, const u16* g) {
    u16* d = lds + (((bb * 4 + rr) * 16) + w * 2) * 512;
    gld_lds16(g, d);             // kstep 0: cols +0..31
    gld_lds16(g + 32, d + 512);  // kstep 1: cols +32..63
  };

  // prologue: tile 0 fully + tile 1's A halves
  STAGEH(0, 0, gA0);
  STAGEH(0, 1, gA1);
  STAGEH(0, 2, gB0);
  STAGEH(0, 3, gB1);
  if (nkt > 1) {
    STAGEH(1, 0, gA0 + 64);
    STAGEH(1, 1, gA1 + 64);
  }
  VMCNT4();  // tile 0's 8 loads landed; tile-1-A's 4 in flight
  SBAR();

  bf16x8 arLo[4][2], arHi[4][2], br[2][2];

  // pre-loop region P0(0): stage B0(1); read arLo(0), brA(0)
  {
    if (1 < nkt) STAGEH(1, 2, gB0 + 64);
    const u16* bufA = lds + ((0 * 4 + wm) * 16) * 512 + lane * 8;
    const u16* bufB = lds + ((0 * 4 + 2 + (wn >> 1)) * 16) * 512 + lane * 8;
#pragma unroll
    for (int fr = 0; fr < 4; ++fr)
#pragma unroll
      for (int ks = 0; ks < 2; ++ks)
        arLo[fr][ks] = *reinterpret_cast<const bf16x8*>(bufA + (fr * 2 + ks) * 512);
#pragma unroll
    for (int nc = 0; nc < 2; ++nc)
#pragma unroll
      for (int ks = 0; ks < 2; ++ks)
        br[nc][ks] = *reinterpret_cast<const bf16x8*>(bufB + ((bf0 + nc) * 2 + ks) * 512);
    SBAR();
  }

  // One K-tile: 4 barrier regions (P1, P2, P3, P0' of next tile).
  auto kbody = [&](int T, int b) {
    const u16* bufA = lds + ((b * 4 + wm) * 16) * 512 + lane * 8;
    const u16* bufB = lds + ((b * 4 + 2 + (wn >> 1)) * 16) * 512 + lane * 8;
    const u16* bufAn = lds + (((b ^ 1) * 4 + wm) * 16) * 512 + lane * 8;
    const u16* bufBn = lds + (((b ^ 1) * 4 + 2 + (wn >> 1)) * 16) * 512 + lane * 8;

    // ---- P1: stage B1(T+1); MFMA C0 = arLo x brA; read arHi(T); bar
    if (T + 1 < nkt) STAGEH(b ^ 1, 3, gB1 + (size_t)(T + 1) * 64);
    __builtin_amdgcn_s_setprio(1);
#pragma unroll
    for (int fr = 0; fr < 4; ++fr)
#pragma unroll
      for (int nc = 0; nc < 2; ++nc)
#pragma unroll
        for (int ks = 0; ks < 2; ++ks)
          acc[fr][nc] = __builtin_amdgcn_mfma_f32_16x16x32_bf16(arLo[fr][ks], br[nc][ks],
                                                                acc[fr][nc], 0, 0, 0);
    __builtin_amdgcn_s_setprio(0);
#pragma unroll
    for (int fr = 0; fr < 4; ++fr)
#pragma unroll
      for (int ks = 0; ks < 2; ++ks)
        arHi[fr][ks] = *reinterpret_cast<const bf16x8*>(bufA + ((fr + 4) * 2 + ks) * 512);
    SBAR();

    // ---- P2: stage A0(T+2); MFMA C1 = arHi x brA; read brB(T); bar
    if (T + 2 < nkt) STAGEH(b, 0, gA0 + (size_t)(T + 2) * 64);
    __builtin_amdgcn_s_setprio(1);
#pragma unroll
    for (int fr = 0; fr < 4; ++fr)
#pragma unroll
      for (int nc = 0; nc < 2; ++nc)
#pragma unroll
        for (int ks = 0; ks < 2; ++ks)
          acc[4 + fr][nc] = __builtin_amdgcn_mfma_f32_16x16x32_bf16(arHi[fr][ks], br[nc][ks],
                                                                    acc[4 + fr][nc], 0, 0, 0);
    __builtin_amdgcn_s_setprio(0);
#pragma unroll
    for (int nc = 0; nc < 2; ++nc)
#pragma unroll
      for (int ks = 0; ks < 2; ++ks)
        br[nc][ks] = *reinterpret_cast<const bf16x8*>(bufB + ((bf0 + 2 + nc) * 2 + ks) * 512);
    SBAR();

    // ---- P3: stage A1(T+2); MFMA C2 = arHi x brB; boundary vmcnt; bar
    if (T + 2 < nkt) STAGEH(b, 1, gA1 + (size_t)(T + 2) * 64);
    __builtin_amdgcn_s_setprio(1);
#pragma unroll
    for (int fr = 0; fr < 4; ++fr)
#pragma unroll
      for (int nc = 0; nc < 2; ++nc)
#pragma unroll
        for (int ks = 0; ks < 2; ++ks)
          acc[4 + fr][2 + nc] = __builtin_amdgcn_mfma_f32_16x16x32_bf16(arHi[fr][ks], br[nc][ks],
                                                                        acc[4 + fr][2 + nc], 0, 0, 0);
    __builtin_amdgcn_s_setprio(0);
    if (T + 2 < nkt) {
      VMCNT4();  // retires tile-(T+1)'s 8 loads, leaves A(T+2)
    } else {
      VMCNT0();  // no A(T+2) staged: drain so tile T+1 (if any) is landed
    }
    SBAR();

    // ---- P0(T+1): stage B0(T+2); MFMA C3 = arLo x brB; read arLo/brA(T+1); bar
    if (T + 2 < nkt) STAGEH(b, 2, gB0 + (size_t)(T + 2) * 64);
    __builtin_amdgcn_s_setprio(1);
#pragma unroll
    for (int fr = 0; fr < 4; ++fr)
#pragma unroll
      for (int nc = 0; nc < 2; ++nc)
#pragma unroll
        for (int ks = 0; ks < 2; ++ks)
          acc[fr][2 + nc] = __builtin_amdgcn_mfma_f32_16x16x32_bf16(arLo[fr][ks], br[nc][ks],
                                                                    acc[fr][2 + nc], 0, 0, 0);
    __builtin_amdgcn_s_setprio(0);
    if (T + 1 < nkt) {
#pragma unroll
      for (int fr = 0; fr < 4; ++fr)
#pragma unroll
        for (int ks = 0; ks < 2; ++ks)
          arLo[fr][ks] = *reinterpret_cast<const bf16x8*>(bufAn + (fr * 2 + ks) * 512);
#pragma unroll
      for (int nc = 0; nc < 2; ++nc)
#pragma unroll
        for (int ks = 0; ks < 2; ++ks)
          br[nc][ks] = *reinterpret_cast<const bf16x8*>(bufBn + ((bf0 + nc) * 2 + ks) * 512);
    }
    SBAR();
  };

  for (int TT = 0; TT < nkt; TT += 2) {  // nkt even at all call sites
    kbody(TT, 0);
    kbody(TT + 1, 1);
  }

  // epilogue: row = r0 + fr*16 + i, col = c0 + nc*16 (tile-local)
  epi(acc, wm * 128 + l16 * 4, wn * 64 + l15);
}

// ---------------------------------------------------------------------------
__global__ __launch_bounds__(256) void k_cvt_x(const float* __restrict__ x,
                                               u16* __restrict__ xb) {
  const int idx = (blockIdx.x * 256 + threadIdx.x) * 4;
  const float4 v = *reinterpret_cast<const float4*>(x + idx);
  ushort4 o;
  o.x = f2bf(v.x); o.y = f2bf(v.y); o.z = f2bf(v.z); o.w = f2bf(v.w);
  *reinterpret_cast<ushort4*>(xb + idx) = o;
}

// W [DIN][DOUT] fp32 -> Wt [DOUT][DIN] bf16 (tiled transpose via LDS)
__global__ __launch_bounds__(256) void k_cvt_wt(const float* __restrict__ W,
                                                u16* __restrict__ Wt) {
  __shared__ u16 tile[64][65];
  const int bc = blockIdx.x;
  const int tr0 = (bc >> 4) * 64;
  const int tc0 = (bc & 15) * 64;
  const int t = threadIdx.x;
  const int col = t & 63, rr = t >> 6;
#pragma unroll
  for (int p = 0; p < 16; ++p) {
    const int row = rr * 16 + p;
    tile[row][col] = f2bf(W[(size_t)(tr0 + row) * DOUT + tc0 + col]);
  }
  __syncthreads();
#pragma unroll
  for (int p = 0; p < 16; ++p) {
    const int row = rr * 16 + p;
    Wt[(size_t)(tc0 + row) * DIN + tr0 + col] = tile[col][row];
  }
}

// Fused QKV projection. 768 blocks, XCD-swizzled; n-tiles 0-7 -> qk row-major,
// 8-11 -> vT transposed.
__global__ __launch_bounds__(512, 2) void k_proj(const u16* __restrict__ xb,
                                                 const u16* __restrict__ Wt,
                                                 u16* __restrict__ qkb,
                                                 u16* __restrict__ vT) {
  const int wg = (blockIdx.x & 7) * 96 + (blockIdx.x >> 3);  // bijective, 768%8==0
  const int m0 = (wg / 12) * 256, n0 = (wg % 12) * 256;
  gemm256(xb, DIN, Wt, DIN, m0, n0, DIN,
          [&](const f32x4(&acc)[8][4], int r0, int c0) {
            if (n0 < 2 * DOUT) {  // q or k -> qkb row-major [16384][2048]
#pragma unroll
              for (int fr = 0; fr < 8; ++fr)
#pragma unroll
                for (int nc = 0; nc < 4; ++nc) {
                  const int r = m0 + r0 + fr * 16;
                  const int c = n0 + c0 + nc * 16;
#pragma unroll
                  for (int i = 0; i < 4; ++i)
                    qkb[(size_t)(r + i) * 2048 + c] = f2bf(acc[fr][nc][i]);
                }
            } else {  // v -> vT[b][d][s]
              const int b = m0 >> 11;
              const int sl = (m0 & (CTX - 1)) + r0;
              u16* C = vT + (size_t)b * DOUT * CTX;
#pragma unroll
              for (int fr = 0; fr < 8; ++fr)
#pragma unroll
                for (int nc = 0; nc < 4; ++nc) {
                  const int d = n0 - 2 * DOUT + c0 + nc * 16;
                  const int s = sl + fr * 16;
                  ushort4 o;
                  o.x = f2bf(acc[fr][nc][0]);
                  o.y = f2bf(acc[fr][nc][1]);
                  o.z = f2bf(acc[fr][nc][2]);
                  o.w = f2bf(acc[fr][nc][3]);
                  *reinterpret_cast<ushort4*>(C + (size_t)d * CTX + s) = o;
                }
            }
          });
}

// S[b][i][j] = (q.k)/32, lower-triangular 256x256 tiles (36 per batch)
__global__ __launch_bounds__(512, 2) void k_score(const u16* __restrict__ qkb,
                                                  float* __restrict__ S) {
  const int u = (blockIdx.x & 7) * 36 + (blockIdx.x >> 3);  // 288%8==0
  const int b = u / 36, v = u % 36;
  int it = 0;
  while ((it + 1) * (it + 2) / 2 <= v) ++it;
  const int jt = v - it * (it + 1) / 2;
  const u16* Aq = qkb + (size_t)b * CTX * 2048;
  float* C = S + ((size_t)b << 22);
  const int m0 = it * 256, n0 = jt * 256;
  gemm256(Aq, 2048, Aq + 1024, 2048, m0, n0, DOUT,
          [&](const f32x4(&acc)[8][4], int r0, int c0) {
#pragma unroll
            for (int fr = 0; fr < 8; ++fr)
#pragma unroll
              for (int nc = 0; nc < 4; ++nc) {
                const int r = m0 + r0 + fr * 16;
                const int c = n0 + c0 + nc * 16;
#pragma unroll
                for (int i = 0; i < 4; ++i)
                  C[(size_t)(r + i) * CTX + c] = acc[fr][nc][i] * 0.03125f;
              }
          });
}

// row softmax over S fp32, write P bf16 in place (row stride 4096 u16),
// full 2048 cols written (zeros above diagonal) so PV GEMM needs no masking.
__global__ __launch_bounds__(256) void k_softmax(float* __restrict__ Sws) {
  const int row = blockIdx.x;
  const int b = row >> 11, i = row & (CTX - 1);
  const float* srow = Sws + ((size_t)b << 22) + ((size_t)i << 11);
  u16* prow = (u16*)(Sws + ((size_t)b << 22)) + ((size_t)i << 12);
  const int t = threadIdx.x;
  const int j0 = t * 8;
  float vv[8];
  if (j0 <= i) {
    const float4 v0 = *reinterpret_cast<const float4*>(srow + j0);
    const float4 v1 = *reinterpret_cast<const float4*>(srow + j0 + 4);
    vv[0] = v0.x; vv[1] = v0.y; vv[2] = v0.z; vv[3] = v0.w;
    vv[4] = v1.x; vv[5] = v1.y; vv[6] = v1.z; vv[7] = v1.w;
  } else {
#pragma unroll
    for (int p = 0; p < 8; ++p) vv[p] = -3.0e38f;
  }
  float mx = -3.0e38f;
#pragma unroll
  for (int p = 0; p < 8; ++p) {
    vv[p] = (j0 + p <= i) ? vv[p] : -3.0e38f;
    mx = fmaxf(mx, vv[p]);
  }
#pragma unroll
  for (int off = 32; off > 0; off >>= 1) mx = fmaxf(mx, __shfl_xor(mx, off));
  __shared__ float redm[4], reds[4];
  const int lane = t & 63, wid = t >> 6;
  if (lane == 0) redm[wid] = mx;
  __syncthreads();
  mx = fmaxf(fmaxf(redm[0], redm[1]), fmaxf(redm[2], redm[3]));
  float e[8], s = 0.f;
#pragma unroll
  for (int p = 0; p < 8; ++p) {
    e[p] = __expf(vv[p] - mx);
    s += e[p];
  }
#pragma unroll
  for (int off = 32; off > 0; off >>= 1) s += __shfl_xor(s, off);
  if (lane == 0) reds[wid] = s;
  __syncthreads();  // orders row reads above before in-place writes below
  s = reds[0] + reds[1] + reds[2] + reds[3];
  const float inv = 1.0f / s;
  ushort4 o0, o1;
  o0.x = (j0 + 0 <= i) ? f2bf(e[0] * inv) : (u16)0;
  o0.y = (j0 + 1 <= i) ? f2bf(e[1] * inv) : (u16)0;
  o0.z = (j0 + 2 <= i) ? f2bf(e[2] * inv) : (u16)0;
  o0.w = (j0 + 3 <= i) ? f2bf(e[3] * inv) : (u16)0;
  o1.x = (j0 + 4 <= i) ? f2bf(e[4] * inv) : (u16)0;
  o1.y = (j0 + 5 <= i) ? f2bf(e[5] * inv) : (u16)0;
  o1.z = (j0 + 6 <= i) ? f2bf(e[6] * inv) : (u16)0;
  o1.w = (j0 + 7 <= i) ? f2bf(e[7] * inv) : (u16)0;
  *reinterpret_cast<ushort4*>(prow + j0) = o0;
  *reinterpret_cast<ushort4*>(prow + j0 + 4) = o1;
}

// out[b][i][d] = sum_j P[b][i][j] * V[b][j][d]; K causally limited; LPT order.
__global__ __launch_bounds__(512, 2) void k_out(const float* __restrict__ Sws,
                                                const u16* __restrict__ vT,
                                                float* __restrict__ out) {
  const int idx = blockIdx.x;          // 256 blocks = 8it x 8b x 4nt
  const int it = 7 - (idx >> 5);       // longest (K=2048) first
  const int b = (idx >> 2) & 7;
  const int nt = idx & 3;
  const u16* P = (const u16*)(Sws + ((size_t)b << 22));  // lda = 4096 u16
  const u16* Bt = vT + (size_t)b * DOUT * CTX;           // [D][S]
  float* C = out + (size_t)b * CTX * DOUT;
  const int m0 = it * 256, n0 = nt * 256;
  gemm256(P, 2 * CTX, Bt, CTX, m0, n0, (it + 1) * 256,
          [&](const f32x4(&acc)[8][4], int r0, int c0) {
#pragma unroll
            for (int fr = 0; fr < 8; ++fr)
#pragma unroll
              for (int nc = 0; nc < 4; ++nc) {
                const int r = m0 + r0 + fr * 16;
                const int c = n0 + c0 + nc * 16;
#pragma unroll
                for (int i = 0; i < 4; ++i)
                  C[(size_t)(r + i) * DOUT + c] = acc[fr][nc][i];
              }
          });
}

// ---------------------------------------------------------------------------
extern "C" void kernel_launch(void* const* d_in, const int* in_sizes, int n_in,
                              void* d_out, int out_size, void* d_ws, size_t ws_size,
                              hipStream_t stream) {
  (void)in_sizes; (void)n_in; (void)out_size; (void)ws_size;
  const float* x = (const float*)d_in[0];
  const float* Wq = (const float*)d_in[1];
  const float* Wk = (const float*)d_in[2];
  const float* Wv = (const float*)d_in[3];
  float* out = (float*)d_out;
  uint8_t* ws = (uint8_t*)d_ws;

  // ws layout (224 MB):
  //   [0,128M): S fp32 [8][2048][2048] (P bf16 written in place by softmax)
  //     xb bf16 (32MB) + Wt_all (6MB) overlap S -- dead before k_score runs
  //   [128M,192M): qkb bf16 [8][2048][2048] (q cols 0..1023, k cols 1024..2047)
  //   [192M,224M): vT bf16 [8][1024][2048]
  float* S = (float*)ws;
  u16* xb = (u16*)ws;
  u16* Wt_all = (u16*)(ws + 33554432ull);  // [3072][1024]: q|k|v
  u16* qkb = (u16*)(ws + 134217728ull);
  u16* vT = (u16*)(ws + 201326592ull);

  k_cvt_x<<<16384, 256, 0, stream>>>(x, xb);
  k_cvt_wt<<<256, 256, 0, stream>>>(Wq, Wt_all);
  k_cvt_wt<<<256, 256, 0, stream>>>(Wk, Wt_all + 1024ull * 1024);
  k_cvt_wt<<<256, 256, 0, stream>>>(Wv, Wt_all + 2048ull * 1024);
  k_proj<<<768, 512, 0, stream>>>(xb, Wt_all, qkb, vT);
  k_score<<<288, 512, 0, stream>>>(qkb, S);
  k_softmax<<<NB * CTX, 256, 0, stream>>>(S);
  k_out<<<256, 512, 0, stream>>>(S, vT, out);
}